// Round 8
// baseline (260.261 us; speedup 1.0000x reference)
//
#include <hip/hip_runtime.h>

// out[b,p,c] = sum_s (x[b,s,c]-x[b,S-1,c]) * W[c,p,s] + bias[c,p] + x[b,S-1,c]
//   1) xpose: x'(c,b,s) = bf16(x[b,s,c]-x[b,S-1,c]) into d_ws, with the gemm
//      A-swizzle PRE-BAKED into the global layout (16B octet o -> o^((b>>1)&3)
//      within each 64B s-group) so gemm can global_load_lds linearly.
//   2) gemm : 8 waves, tile 128b x 96p x 2c. A via global_load_lds (async,
//      vmcnt-counted); W fp32 reg-staged depth-2 -> bf16 -> LDS. RAW s_barrier
//      with counted vmcnt (never drain to 0 in the loop) — T3/T4 pattern.

typedef __attribute__((ext_vector_type(8))) short short8;   // 8 bf16
typedef __attribute__((ext_vector_type(4))) float floatx4;  // MFMA C/D

namespace {
constexpr int Bn = 128, Sn = 672, Pn = 168, Cn = 500;
constexpr int XQ_CSTRIDE = Bn * Sn;
constexpr int TC = 64, TS = 96, TROW = TS + 12;   // xpose tile
constexpr int BC   = 2;               // c-planes per block (500 = 2*250)
constexpr int BPAD = 96;              // padded p-extent (2 tiles cover 168)
constexpr int NSCH = Sn / 32;         // 21 chunks of 32 s
constexpr int A_ELE = BC * Bn * 32;   // 8192 ushort = 16 KB
constexpr int W_ELE = BC * BPAD * 32; // 6144 ushort = 12 KB
constexpr int NWORK = 500;
}

__device__ __forceinline__ unsigned short f2bf(float f) {  // RTNE f32->bf16
  unsigned int u = __builtin_bit_cast(unsigned int, f);
  u += 0x7fffu + ((u >> 16) & 1u);
  return (unsigned short)(u >> 16);
}

__device__ __forceinline__ void gload16(const unsigned short* g, unsigned short* l) {
  __builtin_amdgcn_global_load_lds(
      (const __attribute__((address_space(1))) unsigned int*)g,
      (__attribute__((address_space(3))) unsigned int*)l, 16, 0, 0);
}

// ---------------------------------------------------------------- xpose ----
// Writes x' pre-swizzled: within each (c,b) row's 64B s-group, the 16B octet
// at logical position o is stored at o ^ ((b>>1)&3). gemm reads it back with
// the matching XOR on the LDS side.
__global__ __launch_bounds__(256)
void xpose_kernel(const float* __restrict__ x, unsigned short* __restrict__ xq) {
  __shared__ unsigned short T[TC][TROW];
  const int b  = blockIdx.x;
  const int s0 = blockIdx.y * TS;       // multiple of 32
  const int c0 = blockIdx.z * TC;
  const int t  = threadIdx.x;
  const int sw = (b >> 1) & 3;          // per-row octet swizzle

  #pragma unroll
  for (int i = 0; i < 6; ++i) {
    const int idx = t + i * 256;       // 96 s-rows x 16 c-quads
    const int sr  = idx >> 4;
    const int cq  = (idx & 15) * 4;
    int c = c0 + cq;
    if (c > Cn - 4) c = Cn - 4;        // clamp (16B-aligned); dup writes identical
    const int rel = c - c0;
    const float4 xv = *(const float4*)&x[(size_t)(b * Sn + s0 + sr) * Cn + c];
    const float4 xl = *(const float4*)&x[(size_t)(b * Sn + (Sn - 1)) * Cn + c];
    T[rel + 0][sr] = f2bf(xv.x - xl.x);
    T[rel + 1][sr] = f2bf(xv.y - xl.y);
    T[rel + 2][sr] = f2bf(xv.z - xl.z);
    T[rel + 3][sr] = f2bf(xv.w - xl.w);
  }
  __syncthreads();
  #pragma unroll
  for (int i = 0; i < 6; ++i) {
    const int idx = t + i * 256;       // 64 c-rows x 24 s-quads
    const int cr  = idx / 24;
    const int sq  = (idx % 24) * 4;
    const int c   = c0 + cr;
    if (c >= Cn) continue;
    const ushort4 v = *(const ushort4*)&T[cr][sq];
    // swizzled position within the 32-s group
    const int o   = (sq >> 3) & 3;
    const int sqw = (sq & ~31) | (((o ^ sw) & 3) << 3) | (sq & 7);
    *(ushort4*)&xq[(size_t)c * XQ_CSTRIDE + b * Sn + s0 + sqw] = v;
  }
}

// ----------------------------------------------------------------- gemm ----
#define WAIT_BAR(N) asm volatile("s_waitcnt vmcnt(" #N ") lgkmcnt(0)\n\ts_barrier" ::: "memory")

__global__ __launch_bounds__(512, 4)
void gemm_kernel(const unsigned short* __restrict__ xq, const float* __restrict__ W,
                 const float* __restrict__ bias, const float* __restrict__ x,
                 float* __restrict__ out) {
  __shared__ unsigned short As[2][A_ELE];
  __shared__ unsigned short Ws[2][W_ELE];

  const int wid = (blockIdx.x & 7) * 64 + (blockIdx.x >> 3);
  if (wid >= NWORK) return;
  const int pt = wid & 1;
  const int c0 = (wid >> 1) * BC;
  const int p_base = pt * BPAD;

  const int tid  = threadIdx.x;
  const int lane = tid & 63;
  const int wave = tid >> 6;
  const int r16  = lane & 15;
  const int kg   = lane >> 4;
  const int bw   = wave & 3;
  const int pw   = wave >> 2;

  // ---- A staging via global_load_lds: 2 calls/thread, linear LDS dest ----
  int ag[2];
  #pragma unroll
  for (int r = 0; r < 2; ++r) {
    const int idx = r * 512 + tid;
    const int g  = idx & 3;
    const int b  = (idx >> 2) & 127;
    const int cc = idx >> 9;
    ag[r] = (c0 + cc) * XQ_CSTRIDE + b * Sn + g * 8;  // source pre-swizzled
  }
  const int ldsA0 = (wave * 64 + (tid & 63) - (tid & 63)) * 0 + wave * 512; // r=0 base
  const int ldsA1 = 4096 + wave * 512;                                       // r=1 base

  // ---- W staging descriptors: 3 float4 per thread ----
  int wg[3], ww[3];
  #pragma unroll
  for (int r = 0; r < 3; ++r) {
    const int idx  = r * 512 + tid;
    const int q    = idx & 7;
    const int row  = idx >> 3;
    const int cc   = row / BPAD;
    const int prow = row - cc * BPAD;
    int p = p_base + prow;
    if (p >= Pn) p = Pn - 1;
    wg[r] = ((c0 + cc) * Pn + p) * Sn + q * 4;
    const int g = q >> 1, half = q & 1;
    ww[r] = (cc * BPAD + prow) * 32 + ((g ^ ((prow >> 1) & 3)) * 8) + half * 4;
  }

  // ---- compute-side ds_read offsets ----
  int ard[2][2], wrd[2][3];
  #pragma unroll
  for (int cc = 0; cc < 2; ++cc) {
    #pragma unroll
    for (int fb = 0; fb < 2; ++fb) {
      const int row = bw * 32 + fb * 16 + r16;
      ard[cc][fb] = (cc * Bn + row) * 32 + ((kg ^ ((row >> 1) & 3)) * 8);
    }
    #pragma unroll
    for (int fp = 0; fp < 3; ++fp) {
      const int prow = pw * 48 + fp * 16 + r16;
      wrd[cc][fp] = (cc * BPAD + prow) * 32 + ((kg ^ ((prow >> 1) & 3)) * 8);
    }
  }

  floatx4 acc[2][3][2];
  #pragma unroll
  for (int fb = 0; fb < 2; ++fb)
    #pragma unroll
    for (int fp = 0; fp < 3; ++fp)
      #pragma unroll
      for (int cc = 0; cc < 2; ++cc)
        acc[fb][fp][cc] = (floatx4){0.f, 0.f, 0.f, 0.f};

  // ---- W register sets (static names) ----
  float4 s0a, s0b, s0c;   // set0
  float4 s1a, s1b, s1c;   // set1

  auto issueA = [&](int sch, int buf) {
    const int so = sch * 32;
    gload16(xq + ag[0] + so, &As[buf][ldsA0]);
    gload16(xq + ag[1] + so, &As[buf][ldsA1]);
  };
  auto issueW0 = [&](int sch) {
    const int so = sch * 32;
    s0a = *(const float4*)(W + wg[0] + so);
    s0b = *(const float4*)(W + wg[1] + so);
    s0c = *(const float4*)(W + wg[2] + so);
  };
  auto issueW1 = [&](int sch) {
    const int so = sch * 32;
    s1a = *(const float4*)(W + wg[0] + so);
    s1b = *(const float4*)(W + wg[1] + so);
    s1c = *(const float4*)(W + wg[2] + so);
  };
  auto storeW0 = [&](int buf) {
    ushort4 u;
    u.x = f2bf(s0a.x); u.y = f2bf(s0a.y); u.z = f2bf(s0a.z); u.w = f2bf(s0a.w);
    *(ushort4*)&Ws[buf][ww[0]] = u;
    u.x = f2bf(s0b.x); u.y = f2bf(s0b.y); u.z = f2bf(s0b.z); u.w = f2bf(s0b.w);
    *(ushort4*)&Ws[buf][ww[1]] = u;
    u.x = f2bf(s0c.x); u.y = f2bf(s0c.y); u.z = f2bf(s0c.z); u.w = f2bf(s0c.w);
    *(ushort4*)&Ws[buf][ww[2]] = u;
  };
  auto storeW1 = [&](int buf) {
    ushort4 u;
    u.x = f2bf(s1a.x); u.y = f2bf(s1a.y); u.z = f2bf(s1a.z); u.w = f2bf(s1a.w);
    *(ushort4*)&Ws[buf][ww[0]] = u;
    u.x = f2bf(s1b.x); u.y = f2bf(s1b.y); u.z = f2bf(s1b.z); u.w = f2bf(s1b.w);
    *(ushort4*)&Ws[buf][ww[1]] = u;
    u.x = f2bf(s1c.x); u.y = f2bf(s1c.y); u.z = f2bf(s1c.z); u.w = f2bf(s1c.w);
    *(ushort4*)&Ws[buf][ww[2]] = u;
  };
  auto compute = [&](int buf) {
    #pragma unroll
    for (int cc = 0; cc < 2; ++cc) {
      short8 af[2], wf[3];
      #pragma unroll
      for (int fb = 0; fb < 2; ++fb) af[fb] = *(const short8*)&As[buf][ard[cc][fb]];
      #pragma unroll
      for (int fp = 0; fp < 3; ++fp) wf[fp] = *(const short8*)&Ws[buf][wrd[cc][fp]];
      #pragma unroll
      for (int fb = 0; fb < 2; ++fb)
        #pragma unroll
        for (int fp = 0; fp < 3; ++fp)
          acc[fb][fp][cc] =
              __builtin_amdgcn_mfma_f32_16x16x32_bf16(af[fb], wf[fp], acc[fb][fp][cc], 0, 0, 0);
    }
  };

  // ---- prologue ----
  issueA(0, 0);          // A0 -> As[0]  (2 vmem)
  issueW0(0);            // W0 -> set0   (5 vmem... 3 loads)
  issueW1(1);            // W1 -> set1
  storeW0(0);            // Ws[0] <- W0 (compiler reg-dep wait; A0 older -> done too)
  WAIT_BAR(3);           // A0 + W0 done (only set1's 3 loads may remain)

  // ---- main loop: pairs (jj, jj+1), static buffers/sets ----
  #pragma unroll 1
  for (int jj = 0; jj < NSCH - 1; jj += 2) {
    // j = jj (even): read buf0, fill buf1
    issueA(jj + 1, 1);
    issueW0(jj + 2);                 // jj+2 <= 20 always here
    compute(0);
    storeW1(1);                      // Ws[1] <- W jj+1
    WAIT_BAR(3);                     // A jj+1 done; W jj+2 (3 loads) stays in flight
    // j = jj+1 (odd): read buf1, fill buf0
    issueA(jj + 2, 0);
    if (jj < NSCH - 3) {
      issueW1(jj + 3);
      compute(1);
      storeW0(0);                    // Ws[0] <- W jj+2
      WAIT_BAR(3);                   // A jj+2 done; W jj+3 stays in flight
    } else {
      compute(1);
      storeW0(0);
      WAIT_BAR(0);                   // tail: drain (A jj+2 done)
    }
  }
  compute(0);                        // j = NSCH-1 = 20

  // ---- epilogue: out = acc + bias + xlast ----
  float2 xl[2][4];
  #pragma unroll
  for (int fb = 0; fb < 2; ++fb)
    #pragma unroll
    for (int r = 0; r < 4; ++r) {
      const int b = bw * 32 + fb * 16 + kg * 4 + r;
      xl[fb][r] = *(const float2*)&x[(size_t)(b * Sn + Sn - 1) * Cn + c0];
    }
  #pragma unroll
  for (int fp = 0; fp < 3; ++fp) {
    const int p = p_base + pw * 48 + fp * 16 + r16;
    if (p >= Pn) continue;
    const float b0 = bias[(size_t)(c0 + 0) * Pn + p];
    const float b1 = bias[(size_t)(c0 + 1) * Pn + p];
    #pragma unroll
    for (int fb = 0; fb < 2; ++fb)
      #pragma unroll
      for (int r = 0; r < 4; ++r) {
        const int b = bw * 32 + fb * 16 + kg * 4 + r;
        float2 st;
        st.x = acc[fb][fp][0][r] + b0 + xl[fb][r].x;
        st.y = acc[fb][fp][1][r] + b1 + xl[fb][r].y;
        *(float2*)&out[(size_t)(b * Pn + p) * Cn + c0] = st;
      }
  }
}

extern "C" void kernel_launch(void* const* d_in, const int* in_sizes, int n_in,
                              void* d_out, int out_size, void* d_ws, size_t ws_size,
                              hipStream_t stream) {
  (void)in_sizes; (void)n_in; (void)out_size; (void)ws_size;  // needs ws >= 86,016,000 B
  const float* x  = (const float*)d_in[0];
  const float* W  = (const float*)d_in[1];
  const float* bv = (const float*)d_in[2];
  float* out = (float*)d_out;
  unsigned short* xq = (unsigned short*)d_ws;

  hipLaunchKernelGGL(xpose_kernel, dim3(Bn, Sn / TS, (Cn + TC - 1) / TC), dim3(256), 0, stream,
                     x, xq);
  hipLaunchKernelGGL(gemm_kernel, dim3(512), dim3(512), 0, stream,
                     xq, W, bv, x, out);
}

// Round 9
// 259.603 us; speedup vs baseline: 1.0025x; 1.0025x over previous
//
#include <hip/hip_runtime.h>

// out[b,p,c] = sum_s (x[b,s,c]-x[b,S-1,c]) * W[c,p,s] + bias[c,p] + x[b,S-1,c]
//   1) xpose: x'(c,b,s) = bf16(x[b,s,c]-x[b,S-1,c]) into d_ws, with the gemm
//      A-swizzle PRE-BAKED into the global layout (16B octet o -> o^((b>>1)&3)
//      within each 64B s-group) so gemm can global_load_lds linearly.
//   2) gemm : 8 waves, tile 128b x 96p x 2c. A via global_load_lds (async,
//      vmcnt-counted); W fp32 reg-staged depth-2 -> bf16 -> LDS. RAW s_barrier
//      with counted vmcnt (never drain to 0 in the loop).
//   R9: pin amdgpu_waves_per_eu(4,4) -> VGPR budget 128, stop the allocator
//      from chasing the 64-VGPR/8-wave tier via scratch spill (r7/r8 had
//      87-340 MB of spill traffic; VGPR_Count=64 with ~105 live values).

typedef __attribute__((ext_vector_type(8))) short short8;   // 8 bf16
typedef __attribute__((ext_vector_type(4))) float floatx4;  // MFMA C/D

namespace {
constexpr int Bn = 128, Sn = 672, Pn = 168, Cn = 500;
constexpr int XQ_CSTRIDE = Bn * Sn;
constexpr int TC = 64, TS = 96, TROW = TS + 12;   // xpose tile
constexpr int BC   = 2;               // c-planes per block (500 = 2*250)
constexpr int BPAD = 96;              // padded p-extent (2 tiles cover 168)
constexpr int NSCH = Sn / 32;         // 21 chunks of 32 s
constexpr int A_ELE = BC * Bn * 32;   // 8192 ushort = 16 KB
constexpr int W_ELE = BC * BPAD * 32; // 6144 ushort = 12 KB
constexpr int NWORK = 500;
}

__device__ __forceinline__ unsigned short f2bf(float f) {  // RTNE f32->bf16
  unsigned int u = __builtin_bit_cast(unsigned int, f);
  u += 0x7fffu + ((u >> 16) & 1u);
  return (unsigned short)(u >> 16);
}

__device__ __forceinline__ void gload16(const unsigned short* g, unsigned short* l) {
  __builtin_amdgcn_global_load_lds(
      (const __attribute__((address_space(1))) unsigned int*)g,
      (__attribute__((address_space(3))) unsigned int*)l, 16, 0, 0);
}

// ---------------------------------------------------------------- xpose ----
// Writes x' pre-swizzled: within each (c,b) row's 64B s-group, the 16B octet
// at logical position o is stored at o ^ ((b>>1)&3). gemm reads it back with
// the matching XOR on the LDS side.
__global__ __launch_bounds__(256)
void xpose_kernel(const float* __restrict__ x, unsigned short* __restrict__ xq) {
  __shared__ unsigned short T[TC][TROW];
  const int b  = blockIdx.x;
  const int s0 = blockIdx.y * TS;       // multiple of 32
  const int c0 = blockIdx.z * TC;
  const int t  = threadIdx.x;
  const int sw = (b >> 1) & 3;          // per-row octet swizzle

  #pragma unroll
  for (int i = 0; i < 6; ++i) {
    const int idx = t + i * 256;       // 96 s-rows x 16 c-quads
    const int sr  = idx >> 4;
    const int cq  = (idx & 15) * 4;
    int c = c0 + cq;
    if (c > Cn - 4) c = Cn - 4;        // clamp (16B-aligned); dup writes identical
    const int rel = c - c0;
    const float4 xv = *(const float4*)&x[(size_t)(b * Sn + s0 + sr) * Cn + c];
    const float4 xl = *(const float4*)&x[(size_t)(b * Sn + (Sn - 1)) * Cn + c];
    T[rel + 0][sr] = f2bf(xv.x - xl.x);
    T[rel + 1][sr] = f2bf(xv.y - xl.y);
    T[rel + 2][sr] = f2bf(xv.z - xl.z);
    T[rel + 3][sr] = f2bf(xv.w - xl.w);
  }
  __syncthreads();
  #pragma unroll
  for (int i = 0; i < 6; ++i) {
    const int idx = t + i * 256;       // 64 c-rows x 24 s-quads
    const int cr  = idx / 24;
    const int sq  = (idx % 24) * 4;
    const int c   = c0 + cr;
    if (c >= Cn) continue;
    const ushort4 v = *(const ushort4*)&T[cr][sq];
    // swizzled position within the 32-s group
    const int o   = (sq >> 3) & 3;
    const int sqw = (sq & ~31) | (((o ^ sw) & 3) << 3) | (sq & 7);
    *(ushort4*)&xq[(size_t)c * XQ_CSTRIDE + b * Sn + s0 + sqw] = v;
  }
}

// ----------------------------------------------------------------- gemm ----
#define WAIT_BAR(N) asm volatile("s_waitcnt vmcnt(" #N ") lgkmcnt(0)\n\ts_barrier" ::: "memory")

__global__ __launch_bounds__(512)
__attribute__((amdgpu_waves_per_eu(4, 4)))   // pin: 128-VGPR budget, no spill tier-chasing
void gemm_kernel(const unsigned short* __restrict__ xq, const float* __restrict__ W,
                 const float* __restrict__ bias, const float* __restrict__ x,
                 float* __restrict__ out) {
  __shared__ unsigned short As[2][A_ELE];
  __shared__ unsigned short Ws[2][W_ELE];

  const int wid = (blockIdx.x & 7) * 64 + (blockIdx.x >> 3);
  if (wid >= NWORK) return;
  const int pt = wid & 1;
  const int c0 = (wid >> 1) * BC;
  const int p_base = pt * BPAD;

  const int tid  = threadIdx.x;
  const int lane = tid & 63;
  const int wave = tid >> 6;
  const int r16  = lane & 15;
  const int kg   = lane >> 4;
  const int bw   = wave & 3;
  const int pw   = wave >> 2;

  // ---- A staging via global_load_lds: 2 calls/thread, linear LDS dest ----
  int ag[2];
  #pragma unroll
  for (int r = 0; r < 2; ++r) {
    const int idx = r * 512 + tid;
    const int g  = idx & 3;
    const int b  = (idx >> 2) & 127;
    const int cc = idx >> 9;
    ag[r] = (c0 + cc) * XQ_CSTRIDE + b * Sn + g * 8;  // source pre-swizzled
  }
  const int ldsA0 = wave * 512;          // ushort index; lane offset is implicit
  const int ldsA1 = 4096 + wave * 512;

  // ---- W staging descriptors: 3 float4 per thread ----
  int wg[3], ww[3];
  #pragma unroll
  for (int r = 0; r < 3; ++r) {
    const int idx  = r * 512 + tid;
    const int q    = idx & 7;
    const int row  = idx >> 3;
    const int cc   = row / BPAD;
    const int prow = row - cc * BPAD;
    int p = p_base + prow;
    if (p >= Pn) p = Pn - 1;
    wg[r] = ((c0 + cc) * Pn + p) * Sn + q * 4;
    const int g = q >> 1, half = q & 1;
    ww[r] = (cc * BPAD + prow) * 32 + ((g ^ ((prow >> 1) & 3)) * 8) + half * 4;
  }

  // ---- compute-side ds_read offsets ----
  int ard[2][2], wrd[2][3];
  #pragma unroll
  for (int cc = 0; cc < 2; ++cc) {
    #pragma unroll
    for (int fb = 0; fb < 2; ++fb) {
      const int row = bw * 32 + fb * 16 + r16;
      ard[cc][fb] = (cc * Bn + row) * 32 + ((kg ^ ((row >> 1) & 3)) * 8);
    }
    #pragma unroll
    for (int fp = 0; fp < 3; ++fp) {
      const int prow = pw * 48 + fp * 16 + r16;
      wrd[cc][fp] = (cc * BPAD + prow) * 32 + ((kg ^ ((prow >> 1) & 3)) * 8);
    }
  }

  floatx4 acc[2][3][2];
  #pragma unroll
  for (int fb = 0; fb < 2; ++fb)
    #pragma unroll
    for (int fp = 0; fp < 3; ++fp)
      #pragma unroll
      for (int cc = 0; cc < 2; ++cc)
        acc[fb][fp][cc] = (floatx4){0.f, 0.f, 0.f, 0.f};

  // ---- W register sets (static names) ----
  float4 s0a, s0b, s0c;   // set0
  float4 s1a, s1b, s1c;   // set1

  auto issueA = [&](int sch, int buf) {
    const int so = sch * 32;
    gload16(xq + ag[0] + so, &As[buf][ldsA0]);
    gload16(xq + ag[1] + so, &As[buf][ldsA1]);
  };
  auto issueW0 = [&](int sch) {
    const int so = sch * 32;
    s0a = *(const float4*)(W + wg[0] + so);
    s0b = *(const float4*)(W + wg[1] + so);
    s0c = *(const float4*)(W + wg[2] + so);
  };
  auto issueW1 = [&](int sch) {
    const int so = sch * 32;
    s1a = *(const float4*)(W + wg[0] + so);
    s1b = *(const float4*)(W + wg[1] + so);
    s1c = *(const float4*)(W + wg[2] + so);
  };
  auto storeW0 = [&](int buf) {
    ushort4 u;
    u.x = f2bf(s0a.x); u.y = f2bf(s0a.y); u.z = f2bf(s0a.z); u.w = f2bf(s0a.w);
    *(ushort4*)&Ws[buf][ww[0]] = u;
    u.x = f2bf(s0b.x); u.y = f2bf(s0b.y); u.z = f2bf(s0b.z); u.w = f2bf(s0b.w);
    *(ushort4*)&Ws[buf][ww[1]] = u;
    u.x = f2bf(s0c.x); u.y = f2bf(s0c.y); u.z = f2bf(s0c.z); u.w = f2bf(s0c.w);
    *(ushort4*)&Ws[buf][ww[2]] = u;
  };
  auto storeW1 = [&](int buf) {
    ushort4 u;
    u.x = f2bf(s1a.x); u.y = f2bf(s1a.y); u.z = f2bf(s1a.z); u.w = f2bf(s1a.w);
    *(ushort4*)&Ws[buf][ww[0]] = u;
    u.x = f2bf(s1b.x); u.y = f2bf(s1b.y); u.z = f2bf(s1b.z); u.w = f2bf(s1b.w);
    *(ushort4*)&Ws[buf][ww[1]] = u;
    u.x = f2bf(s1c.x); u.y = f2bf(s1c.y); u.z = f2bf(s1c.z); u.w = f2bf(s1c.w);
    *(ushort4*)&Ws[buf][ww[2]] = u;
  };
  auto compute = [&](int buf) {
    #pragma unroll
    for (int cc = 0; cc < 2; ++cc) {
      short8 af[2], wf[3];
      #pragma unroll
      for (int fb = 0; fb < 2; ++fb) af[fb] = *(const short8*)&As[buf][ard[cc][fb]];
      #pragma unroll
      for (int fp = 0; fp < 3; ++fp) wf[fp] = *(const short8*)&Ws[buf][wrd[cc][fp]];
      #pragma unroll
      for (int fb = 0; fb < 2; ++fb)
        #pragma unroll
        for (int fp = 0; fp < 3; ++fp)
          acc[fb][fp][cc] =
              __builtin_amdgcn_mfma_f32_16x16x32_bf16(af[fb], wf[fp], acc[fb][fp][cc], 0, 0, 0);
    }
  };

  // ---- prologue ----
  issueA(0, 0);          // A0 -> As[0]  (2 vmem)
  issueW0(0);            // W0 -> set0
  issueW1(1);            // W1 -> set1
  storeW0(0);            // Ws[0] <- W0 (compiler reg-dep wait; A0 older -> done too)
  WAIT_BAR(3);           // A0 + W0 done (only set1's 3 loads may remain)

  // ---- main loop: pairs (jj, jj+1), static buffers/sets ----
  #pragma unroll 1
  for (int jj = 0; jj < NSCH - 1; jj += 2) {
    // j = jj (even): read buf0, fill buf1
    issueA(jj + 1, 1);
    issueW0(jj + 2);                 // jj+2 <= 20 always here
    compute(0);
    storeW1(1);                      // Ws[1] <- W jj+1
    WAIT_BAR(3);                     // A jj+1 done; W jj+2 (3 loads) stays in flight
    // j = jj+1 (odd): read buf1, fill buf0
    issueA(jj + 2, 0);
    if (jj < NSCH - 3) {
      issueW1(jj + 3);
      compute(1);
      storeW0(0);                    // Ws[0] <- W jj+2
      WAIT_BAR(3);                   // A jj+2 done; W jj+3 stays in flight
    } else {
      compute(1);
      storeW0(0);
      WAIT_BAR(0);                   // tail: drain (A jj+2 done)
    }
  }
  compute(0);                        // j = NSCH-1 = 20

  // ---- epilogue: out = acc + bias + xlast ----
  float2 xl[2][4];
  #pragma unroll
  for (int fb = 0; fb < 2; ++fb)
    #pragma unroll
    for (int r = 0; r < 4; ++r) {
      const int b = bw * 32 + fb * 16 + kg * 4 + r;
      xl[fb][r] = *(const float2*)&x[(size_t)(b * Sn + Sn - 1) * Cn + c0];
    }
  #pragma unroll
  for (int fp = 0; fp < 3; ++fp) {
    const int p = p_base + pw * 48 + fp * 16 + r16;
    if (p >= Pn) continue;
    const float b0 = bias[(size_t)(c0 + 0) * Pn + p];
    const float b1 = bias[(size_t)(c0 + 1) * Pn + p];
    #pragma unroll
    for (int fb = 0; fb < 2; ++fb)
      #pragma unroll
      for (int r = 0; r < 4; ++r) {
        const int b = bw * 32 + fb * 16 + kg * 4 + r;
        float2 st;
        st.x = acc[fb][fp][0][r] + b0 + xl[fb][r].x;
        st.y = acc[fb][fp][1][r] + b1 + xl[fb][r].y;
        *(float2*)&out[(size_t)(b * Pn + p) * Cn + c0] = st;
      }
  }
}

extern "C" void kernel_launch(void* const* d_in, const int* in_sizes, int n_in,
                              void* d_out, int out_size, void* d_ws, size_t ws_size,
                              hipStream_t stream) {
  (void)in_sizes; (void)n_in; (void)out_size; (void)ws_size;  // needs ws >= 86,016,000 B
  const float* x  = (const float*)d_in[0];
  const float* W  = (const float*)d_in[1];
  const float* bv = (const float*)d_in[2];
  float* out = (float*)d_out;
  unsigned short* xq = (unsigned short*)d_ws;

  hipLaunchKernelGGL(xpose_kernel, dim3(Bn, Sn / TS, (Cn + TC - 1) / TC), dim3(256), 0, stream,
                     x, xq);
  hipLaunchKernelGGL(gemm_kernel, dim3(512), dim3(512), 0, stream,
                     xq, W, bv, x, out);
}

// Round 10
// 178.209 us; speedup vs baseline: 1.4604x; 1.4567x over previous
//
#include <hip/hip_runtime.h>

// out[b,p,c] = sum_s (x[b,s,c]-x[b,S-1,c]) * W[c,p,s] + bias[c,p] + x[b,S-1,c]
//   1) xpose: x'(c,b,s) = bf16(x[b,s,c]-x[b,S-1,c]) into d_ws, with the gemm
//      A-swizzle PRE-BAKED into the global layout (16B octet o -> o^((b>>1)&3)
//      within each 64B s-group) so gemm can global_load_lds linearly.
//   2) gemm : 8 waves, tile 128b x 96p x 2c. A via global_load_lds (async,
//      vmcnt-counted); W fp32 reg-staged depth-2 -> bf16 -> LDS. RAW s_barrier
//      with counted vmcnt (never drain to 0 in the loop).
//   R10: __launch_bounds__(512, 2). Session rule: 2nd arg 4 -> allocator
//      squeezes to 64 VGPR and spills (r7-r9: 87-340 MB scratch traffic);
//      2nd arg 2 -> 128 VGPR, no spill (r2). Occupancy is LDS-capped at
//      2 blocks/CU either way, so this costs nothing.

typedef __attribute__((ext_vector_type(8))) short short8;   // 8 bf16
typedef __attribute__((ext_vector_type(4))) float floatx4;  // MFMA C/D

namespace {
constexpr int Bn = 128, Sn = 672, Pn = 168, Cn = 500;
constexpr int XQ_CSTRIDE = Bn * Sn;
constexpr int TC = 64, TS = 96, TROW = TS + 12;   // xpose tile
constexpr int BC   = 2;               // c-planes per block (500 = 2*250)
constexpr int BPAD = 96;              // padded p-extent (2 tiles cover 168)
constexpr int NSCH = Sn / 32;         // 21 chunks of 32 s
constexpr int A_ELE = BC * Bn * 32;   // 8192 ushort = 16 KB
constexpr int W_ELE = BC * BPAD * 32; // 6144 ushort = 12 KB
constexpr int NWORK = 500;
}

__device__ __forceinline__ unsigned short f2bf(float f) {  // RTNE f32->bf16
  unsigned int u = __builtin_bit_cast(unsigned int, f);
  u += 0x7fffu + ((u >> 16) & 1u);
  return (unsigned short)(u >> 16);
}

__device__ __forceinline__ void gload16(const unsigned short* g, unsigned short* l) {
  __builtin_amdgcn_global_load_lds(
      (const __attribute__((address_space(1))) unsigned int*)g,
      (__attribute__((address_space(3))) unsigned int*)l, 16, 0, 0);
}

// ---------------------------------------------------------------- xpose ----
// Writes x' pre-swizzled: within each (c,b) row's 64B s-group, the 16B octet
// at logical position o is stored at o ^ ((b>>1)&3). gemm reads it back with
// the matching XOR on the LDS side.
__global__ __launch_bounds__(256)
void xpose_kernel(const float* __restrict__ x, unsigned short* __restrict__ xq) {
  __shared__ unsigned short T[TC][TROW];
  const int b  = blockIdx.x;
  const int s0 = blockIdx.y * TS;       // multiple of 32
  const int c0 = blockIdx.z * TC;
  const int t  = threadIdx.x;
  const int sw = (b >> 1) & 3;          // per-row octet swizzle

  #pragma unroll
  for (int i = 0; i < 6; ++i) {
    const int idx = t + i * 256;       // 96 s-rows x 16 c-quads
    const int sr  = idx >> 4;
    const int cq  = (idx & 15) * 4;
    int c = c0 + cq;
    if (c > Cn - 4) c = Cn - 4;        // clamp (16B-aligned); dup writes identical
    const int rel = c - c0;
    const float4 xv = *(const float4*)&x[(size_t)(b * Sn + s0 + sr) * Cn + c];
    const float4 xl = *(const float4*)&x[(size_t)(b * Sn + (Sn - 1)) * Cn + c];
    T[rel + 0][sr] = f2bf(xv.x - xl.x);
    T[rel + 1][sr] = f2bf(xv.y - xl.y);
    T[rel + 2][sr] = f2bf(xv.z - xl.z);
    T[rel + 3][sr] = f2bf(xv.w - xl.w);
  }
  __syncthreads();
  #pragma unroll
  for (int i = 0; i < 6; ++i) {
    const int idx = t + i * 256;       // 64 c-rows x 24 s-quads
    const int cr  = idx / 24;
    const int sq  = (idx % 24) * 4;
    const int c   = c0 + cr;
    if (c >= Cn) continue;
    const ushort4 v = *(const ushort4*)&T[cr][sq];
    // swizzled position within the 32-s group
    const int o   = (sq >> 3) & 3;
    const int sqw = (sq & ~31) | (((o ^ sw) & 3) << 3) | (sq & 7);
    *(ushort4*)&xq[(size_t)c * XQ_CSTRIDE + b * Sn + s0 + sqw] = v;
  }
}

// ----------------------------------------------------------------- gemm ----
#define WAIT_BAR(N) asm volatile("s_waitcnt vmcnt(" #N ") lgkmcnt(0)\n\ts_barrier" ::: "memory")

__global__ __launch_bounds__(512, 2)   // min-waves=2: 128-VGPR budget, no spill (r2 rule)
void gemm_kernel(const unsigned short* __restrict__ xq, const float* __restrict__ W,
                 const float* __restrict__ bias, const float* __restrict__ x,
                 float* __restrict__ out) {
  __shared__ unsigned short As[2][A_ELE];
  __shared__ unsigned short Ws[2][W_ELE];

  const int wid = (blockIdx.x & 7) * 64 + (blockIdx.x >> 3);
  if (wid >= NWORK) return;
  const int pt = wid & 1;
  const int c0 = (wid >> 1) * BC;
  const int p_base = pt * BPAD;

  const int tid  = threadIdx.x;
  const int lane = tid & 63;
  const int wave = tid >> 6;
  const int r16  = lane & 15;
  const int kg   = lane >> 4;
  const int bw   = wave & 3;
  const int pw   = wave >> 2;

  // ---- A staging via global_load_lds: 2 calls/thread, linear LDS dest ----
  int ag[2];
  #pragma unroll
  for (int r = 0; r < 2; ++r) {
    const int idx = r * 512 + tid;
    const int g  = idx & 3;
    const int b  = (idx >> 2) & 127;
    const int cc = idx >> 9;
    ag[r] = (c0 + cc) * XQ_CSTRIDE + b * Sn + g * 8;  // source pre-swizzled
  }
  const int ldsA0 = wave * 512;          // ushort index; lane offset implicit
  const int ldsA1 = 4096 + wave * 512;

  // ---- W staging descriptors: 3 float4 per thread ----
  int wg[3], ww[3];
  #pragma unroll
  for (int r = 0; r < 3; ++r) {
    const int idx  = r * 512 + tid;
    const int q    = idx & 7;
    const int row  = idx >> 3;
    const int cc   = row / BPAD;
    const int prow = row - cc * BPAD;
    int p = p_base + prow;
    if (p >= Pn) p = Pn - 1;
    wg[r] = ((c0 + cc) * Pn + p) * Sn + q * 4;
    const int g = q >> 1, half = q & 1;
    ww[r] = (cc * BPAD + prow) * 32 + ((g ^ ((prow >> 1) & 3)) * 8) + half * 4;
  }

  // ---- compute-side ds_read offsets ----
  int ard[2][2], wrd[2][3];
  #pragma unroll
  for (int cc = 0; cc < 2; ++cc) {
    #pragma unroll
    for (int fb = 0; fb < 2; ++fb) {
      const int row = bw * 32 + fb * 16 + r16;
      ard[cc][fb] = (cc * Bn + row) * 32 + ((kg ^ ((row >> 1) & 3)) * 8);
    }
    #pragma unroll
    for (int fp = 0; fp < 3; ++fp) {
      const int prow = pw * 48 + fp * 16 + r16;
      wrd[cc][fp] = (cc * BPAD + prow) * 32 + ((kg ^ ((prow >> 1) & 3)) * 8);
    }
  }

  floatx4 acc[2][3][2];
  #pragma unroll
  for (int fb = 0; fb < 2; ++fb)
    #pragma unroll
    for (int fp = 0; fp < 3; ++fp)
      #pragma unroll
      for (int cc = 0; cc < 2; ++cc)
        acc[fb][fp][cc] = (floatx4){0.f, 0.f, 0.f, 0.f};

  // ---- W register sets (static names) ----
  float4 s0a, s0b, s0c;   // set0
  float4 s1a, s1b, s1c;   // set1

  auto issueA = [&](int sch, int buf) {
    const int so = sch * 32;
    gload16(xq + ag[0] + so, &As[buf][ldsA0]);
    gload16(xq + ag[1] + so, &As[buf][ldsA1]);
  };
  auto issueW0 = [&](int sch) {
    const int so = sch * 32;
    s0a = *(const float4*)(W + wg[0] + so);
    s0b = *(const float4*)(W + wg[1] + so);
    s0c = *(const float4*)(W + wg[2] + so);
  };
  auto issueW1 = [&](int sch) {
    const int so = sch * 32;
    s1a = *(const float4*)(W + wg[0] + so);
    s1b = *(const float4*)(W + wg[1] + so);
    s1c = *(const float4*)(W + wg[2] + so);
  };
  auto storeW0 = [&](int buf) {
    ushort4 u;
    u.x = f2bf(s0a.x); u.y = f2bf(s0a.y); u.z = f2bf(s0a.z); u.w = f2bf(s0a.w);
    *(ushort4*)&Ws[buf][ww[0]] = u;
    u.x = f2bf(s0b.x); u.y = f2bf(s0b.y); u.z = f2bf(s0b.z); u.w = f2bf(s0b.w);
    *(ushort4*)&Ws[buf][ww[1]] = u;
    u.x = f2bf(s0c.x); u.y = f2bf(s0c.y); u.z = f2bf(s0c.z); u.w = f2bf(s0c.w);
    *(ushort4*)&Ws[buf][ww[2]] = u;
  };
  auto storeW1 = [&](int buf) {
    ushort4 u;
    u.x = f2bf(s1a.x); u.y = f2bf(s1a.y); u.z = f2bf(s1a.z); u.w = f2bf(s1a.w);
    *(ushort4*)&Ws[buf][ww[0]] = u;
    u.x = f2bf(s1b.x); u.y = f2bf(s1b.y); u.z = f2bf(s1b.z); u.w = f2bf(s1b.w);
    *(ushort4*)&Ws[buf][ww[1]] = u;
    u.x = f2bf(s1c.x); u.y = f2bf(s1c.y); u.z = f2bf(s1c.z); u.w = f2bf(s1c.w);
    *(ushort4*)&Ws[buf][ww[2]] = u;
  };
  auto compute = [&](int buf) {
    #pragma unroll
    for (int cc = 0; cc < 2; ++cc) {
      short8 af[2], wf[3];
      #pragma unroll
      for (int fb = 0; fb < 2; ++fb) af[fb] = *(const short8*)&As[buf][ard[cc][fb]];
      #pragma unroll
      for (int fp = 0; fp < 3; ++fp) wf[fp] = *(const short8*)&Ws[buf][wrd[cc][fp]];
      #pragma unroll
      for (int fb = 0; fb < 2; ++fb)
        #pragma unroll
        for (int fp = 0; fp < 3; ++fp)
          acc[fb][fp][cc] =
              __builtin_amdgcn_mfma_f32_16x16x32_bf16(af[fb], wf[fp], acc[fb][fp][cc], 0, 0, 0);
    }
  };

  // ---- prologue ----
  issueA(0, 0);          // A0 -> As[0]  (2 vmem)
  issueW0(0);            // W0 -> set0
  issueW1(1);            // W1 -> set1
  storeW0(0);            // Ws[0] <- W0 (compiler reg-dep wait; A0 older -> done too)
  WAIT_BAR(3);           // A0 + W0 done (only set1's 3 loads may remain)

  // ---- main loop: pairs (jj, jj+1), static buffers/sets ----
  #pragma unroll 1
  for (int jj = 0; jj < NSCH - 1; jj += 2) {
    // j = jj (even): read buf0, fill buf1
    issueA(jj + 1, 1);
    issueW0(jj + 2);                 // jj+2 <= 20 always here
    compute(0);
    storeW1(1);                      // Ws[1] <- W jj+1
    WAIT_BAR(3);                     // A jj+1 done; W jj+2 (3 loads) stays in flight
    // j = jj+1 (odd): read buf1, fill buf0
    issueA(jj + 2, 0);
    if (jj < NSCH - 3) {
      issueW1(jj + 3);
      compute(1);
      storeW0(0);                    // Ws[0] <- W jj+2
      WAIT_BAR(3);                   // A jj+2 done; W jj+3 stays in flight
    } else {
      compute(1);
      storeW0(0);
      WAIT_BAR(0);                   // tail: drain (A jj+2 done)
    }
  }
  compute(0);                        // j = NSCH-1 = 20

  // ---- epilogue: out = acc + bias + xlast ----
  float2 xl[2][4];
  #pragma unroll
  for (int fb = 0; fb < 2; ++fb)
    #pragma unroll
    for (int r = 0; r < 4; ++r) {
      const int b = bw * 32 + fb * 16 + kg * 4 + r;
      xl[fb][r] = *(const float2*)&x[(size_t)(b * Sn + Sn - 1) * Cn + c0];
    }
  #pragma unroll
  for (int fp = 0; fp < 3; ++fp) {
    const int p = p_base + pw * 48 + fp * 16 + r16;
    if (p >= Pn) continue;
    const float b0 = bias[(size_t)(c0 + 0) * Pn + p];
    const float b1 = bias[(size_t)(c0 + 1) * Pn + p];
    #pragma unroll
    for (int fb = 0; fb < 2; ++fb)
      #pragma unroll
      for (int r = 0; r < 4; ++r) {
        const int b = bw * 32 + fb * 16 + kg * 4 + r;
        float2 st;
        st.x = acc[fb][fp][0][r] + b0 + xl[fb][r].x;
        st.y = acc[fb][fp][1][r] + b1 + xl[fb][r].y;
        *(float2*)&out[(size_t)(b * Pn + p) * Cn + c0] = st;
      }
  }
}

extern "C" void kernel_launch(void* const* d_in, const int* in_sizes, int n_in,
                              void* d_out, int out_size, void* d_ws, size_t ws_size,
                              hipStream_t stream) {
  (void)in_sizes; (void)n_in; (void)out_size; (void)ws_size;  // needs ws >= 86,016,000 B
  const float* x  = (const float*)d_in[0];
  const float* W  = (const float*)d_in[1];
  const float* bv = (const float*)d_in[2];
  float* out = (float*)d_out;
  unsigned short* xq = (unsigned short*)d_ws;

  hipLaunchKernelGGL(xpose_kernel, dim3(Bn, Sn / TS, (Cn + TC - 1) / TC), dim3(256), 0, stream,
                     x, xq);
  hipLaunchKernelGGL(gemm_kernel, dim3(512), dim3(512), 0, stream,
                     xq, W, bv, x, out);
}

// Round 11
// 167.580 us; speedup vs baseline: 1.5531x; 1.0634x over previous
//
#include <hip/hip_runtime.h>

// out[b,p,c] = sum_s (x[b,s,c]-x[b,S-1,c]) * W[c,p,s] + bias[c,p] + x[b,S-1,c]
//   1) xpose: x'(c,b,s) = bf16(x[b,s,c]-x[b,S-1,c]) into d_ws, granule-swizzled
//      (octet o -> o^((b>>1)&3) within each 64B s-group) for gemm's LDS reads.
//   2) gemm R11: BC=1, tile 128b x 176p(pad) x 1c, 704 thr = 11 waves (wave =
//      one 16-p tile). BOTH operands via global_load_lds (W kept fp32 in LDS,
//      converted at frag read). A read once, W read once -> minimal path bytes.
//      60 KB LDS dbuf, ~70-85 VGPR -> 2 blocks/CU co-residency hides barriers.

typedef __attribute__((ext_vector_type(8))) short short8;   // 8 bf16
typedef __attribute__((ext_vector_type(4))) float floatx4;  // MFMA C/D

namespace {
constexpr int Bn = 128, Sn = 672, Pn = 168, Cn = 500;
constexpr int XQ_CSTRIDE = Bn * Sn;
constexpr int TC = 64, TS = 96, TROW = TS + 12;   // xpose tile
constexpr int NSCH = Sn / 32;         // 21 chunks of 32 s
constexpr int PROWS = 176;            // padded p rows (11 tiles of 16)
}

__device__ __forceinline__ unsigned short f2bf(float f) {  // RTNE f32->bf16
  unsigned int u = __builtin_bit_cast(unsigned int, f);
  u += 0x7fffu + ((u >> 16) & 1u);
  return (unsigned short)(u >> 16);
}

__device__ __forceinline__ void gload16u(const unsigned short* g, unsigned short* l) {
  __builtin_amdgcn_global_load_lds(
      (const __attribute__((address_space(1))) unsigned int*)g,
      (__attribute__((address_space(3))) unsigned int*)l, 16, 0, 0);
}
__device__ __forceinline__ void gload16f(const float* g, float* l) {
  __builtin_amdgcn_global_load_lds(
      (const __attribute__((address_space(1))) unsigned int*)g,
      (__attribute__((address_space(3))) unsigned int*)l, 16, 0, 0);
}

// ---------------------------------------------------------------- xpose ----
// (unchanged from r8-r10) pre-swizzled x': within each 64B s-group of a (c,b)
// row, 16B octet o stored at o ^ ((b>>1)&3).
__global__ __launch_bounds__(256)
void xpose_kernel(const float* __restrict__ x, unsigned short* __restrict__ xq) {
  __shared__ unsigned short T[TC][TROW];
  const int b  = blockIdx.x;
  const int s0 = blockIdx.y * TS;       // multiple of 32
  const int c0 = blockIdx.z * TC;
  const int t  = threadIdx.x;
  const int sw = (b >> 1) & 3;

  #pragma unroll
  for (int i = 0; i < 6; ++i) {
    const int idx = t + i * 256;       // 96 s-rows x 16 c-quads
    const int sr  = idx >> 4;
    const int cq  = (idx & 15) * 4;
    int c = c0 + cq;
    if (c > Cn - 4) c = Cn - 4;        // clamp (16B-aligned); dup writes identical
    const int rel = c - c0;
    const float4 xv = *(const float4*)&x[(size_t)(b * Sn + s0 + sr) * Cn + c];
    const float4 xl = *(const float4*)&x[(size_t)(b * Sn + (Sn - 1)) * Cn + c];
    T[rel + 0][sr] = f2bf(xv.x - xl.x);
    T[rel + 1][sr] = f2bf(xv.y - xl.y);
    T[rel + 2][sr] = f2bf(xv.z - xl.z);
    T[rel + 3][sr] = f2bf(xv.w - xl.w);
  }
  __syncthreads();
  #pragma unroll
  for (int i = 0; i < 6; ++i) {
    const int idx = t + i * 256;       // 64 c-rows x 24 s-quads
    const int cr  = idx / 24;
    const int sq  = (idx % 24) * 4;
    const int c   = c0 + cr;
    if (c >= Cn) continue;
    const ushort4 v = *(const ushort4*)&T[cr][sq];
    const int o   = (sq >> 3) & 3;
    const int sqw = (sq & ~31) | (((o ^ sw) & 3) << 3) | (sq & 7);
    *(ushort4*)&xq[(size_t)c * XQ_CSTRIDE + b * Sn + s0 + sqw] = v;
  }
}

// ----------------------------------------------------------------- gemm ----
#define WAIT_BAR(N) asm volatile("s_waitcnt vmcnt(" #N ") lgkmcnt(0)\n\ts_barrier" ::: "memory")

__global__ __launch_bounds__(704, 1)
void gemm_kernel(const unsigned short* __restrict__ xq, const float* __restrict__ W,
                 const float* __restrict__ bias, const float* __restrict__ x,
                 float* __restrict__ out) {
  __shared__ unsigned short As[2][Bn * 32];    // 8 KB each, bf16, swizzled
  __shared__ float          Wsf[2][PROWS * 32]; // 22.5 KB each, fp32, swizzled

  // bijective XCD remap (500 % 8 != 0): consecutive c-planes share an XCD
  const int bid = blockIdx.x;
  const int xcd = bid & 7, sub = bid >> 3;
  const int c0  = xcd * 62 + (xcd < 4 ? xcd : 4) + sub;   // 0..499, runs of 62/63

  const int tid  = threadIdx.x;
  const int lane = tid & 63;
  const int wv   = tid >> 6;          // 0..10 = p-tile of this wave
  const int r16  = lane & 15;
  const int kg   = lane >> 4;

  // ---- A staging (waves 0..7): granule idx = tid: b = tid>>2, pos = tid&3 ----
  const bool aDo = tid < 512;
  const unsigned short* aSrc =
      xq + (size_t)c0 * XQ_CSTRIDE + (tid >> 2) * Sn + (tid & 3) * 8;  // src pre-swizzled
  const int aDst = wv * 512;          // ushort idx, wave-uniform (lanes implicit)

  // ---- W staging: granules tid and tid+704; row = idx>>3, pos = idx&7,
  //      source granule = pos ^ (row&7) (88%8==0 -> same XOR for both) ----
  const int wrow0 = tid >> 3;
  const int wrow1 = wrow0 + 88;
  const int wgp   = (tid & 7) ^ (wrow0 & 7);
  const int p0c = wrow0 < Pn ? wrow0 : Pn - 1;   // clamp pad rows (masked at store)
  const int p1c = wrow1 < Pn ? wrow1 : Pn - 1;
  const float* wSrc0 = W + ((size_t)c0 * Pn + p0c) * Sn + wgp * 4;
  const float* wSrc1 = W + ((size_t)c0 * Pn + p1c) * Sn + wgp * 4;
  const int wDst0 = wv * 256;          // float idx, wave-uniform
  const int wDst1 = wv * 256 + 2816;

  // ---- compute-side offsets ----
  const int wr = wv * 16 + r16;        // logical W row (= p), 0..175
  const int wb_off0 = wr * 32 + (((2 * kg)     ^ (r16 & 7)) * 4);
  const int wb_off1 = wr * 32 + (((2 * kg + 1) ^ (r16 & 7)) * 4);
  const int aswz = (kg ^ ((r16 >> 1) & 3)) * 8;

  floatx4 acc[8];
  #pragma unroll
  for (int bt = 0; bt < 8; ++bt) acc[bt] = (floatx4){0.f, 0.f, 0.f, 0.f};

  auto stage = [&](int sch, int buf) {
    const int so = sch * 32;
    if (aDo) gload16u(aSrc + so, (unsigned short*)As[buf] + aDst);
    gload16f(wSrc0 + so, (float*)Wsf[buf] + wDst0);
    gload16f(wSrc1 + so, (float*)Wsf[buf] + wDst1);
  };
  auto compute = [&](int buf) {
    const float4 wlo = *(const float4*)&Wsf[buf][wb_off0];
    const float4 whi = *(const float4*)&Wsf[buf][wb_off1];
    short8 wb;
    wb[0] = (short)f2bf(wlo.x); wb[1] = (short)f2bf(wlo.y);
    wb[2] = (short)f2bf(wlo.z); wb[3] = (short)f2bf(wlo.w);
    wb[4] = (short)f2bf(whi.x); wb[5] = (short)f2bf(whi.y);
    wb[6] = (short)f2bf(whi.z); wb[7] = (short)f2bf(whi.w);
    #pragma unroll
    for (int bt = 0; bt < 8; ++bt) {
      const short8 a = *(const short8*)&As[buf][(bt * 16 + r16) * 32 + aswz];
      acc[bt] = __builtin_amdgcn_mfma_f32_16x16x32_bf16(a, wb, acc[bt], 0, 0, 0);
    }
  };

  // ---- prologue ----
  stage(0, 0);
  WAIT_BAR(0);

  // ---- main loop: stage j+1 into other buffer, compute j, wait+barrier ----
  #pragma unroll 1
  for (int j = 0; j < NSCH - 1; ++j) {
    stage(j + 1, (j + 1) & 1);
    compute(j & 1);
    WAIT_BAR(0);   // own 2-3 stage loads + ds_reads done; partner block hides this
  }
  compute((NSCH - 1) & 1);   // chunk 20 (buf 0)

  // ---- epilogue: out = acc + bias + xlast ----
  if (wr < Pn) {
    const float bi = bias[(size_t)c0 * Pn + wr];
    #pragma unroll
    for (int bt = 0; bt < 8; ++bt) {
      #pragma unroll
      for (int r = 0; r < 4; ++r) {
        const int b = bt * 16 + kg * 4 + r;   // D row = kg*4 + reg
        const float xl = x[((size_t)b * Sn + (Sn - 1)) * Cn + c0];
        out[((size_t)b * Pn + wr) * Cn + c0] = acc[bt][r] + bi + xl;
      }
    }
  }
}

extern "C" void kernel_launch(void* const* d_in, const int* in_sizes, int n_in,
                              void* d_out, int out_size, void* d_ws, size_t ws_size,
                              hipStream_t stream) {
  (void)in_sizes; (void)n_in; (void)out_size; (void)ws_size;  // needs ws >= 86,016,000 B
  const float* x  = (const float*)d_in[0];
  const float* W  = (const float*)d_in[1];
  const float* bv = (const float*)d_in[2];
  float* out = (float*)d_out;
  unsigned short* xq = (unsigned short*)d_ws;

  hipLaunchKernelGGL(xpose_kernel, dim3(Bn, Sn / TS, (Cn + TC - 1) / TC), dim3(256), 0, stream,
                     x, xq);
  hipLaunchKernelGGL(gemm_kernel, dim3(Cn), dim3(704), 0, stream,
                     xq, W, bv, x, out);
}

// Round 12
// 161.049 us; speedup vs baseline: 1.6160x; 1.0406x over previous
//
#include <hip/hip_runtime.h>

// out[b,p,c] = sum_s (x[b,s,c]-x[b,S-1,c]) * W[c,p,s] + bias[c,p] + x[b,S-1,c]
//   1) xpose: x'(c,b,s) = bf16(x[b,s,c]-x[b,S-1,c]) into d_ws (86 MB), linear.
//   2) gemm R12: block = ONE c-plane (grid 500, XCD c-runs). A = x' c-plane
//      held in REGISTERS (wave owns 16 b; 21 x short8 = 84 VGPR/lane, loaded
//      once). W streamed CONTIGUOUSLY: 11 p-tiles x (16 rows x 672 s fp32 =
//      43 KB sequential) -> cvt bf16 -> LDS dbuf. 21 MFMA per p-tile, acc =
//      4 VGPR. Barriers wait lgkmcnt ONLY; global waits are compiler-counted.
//      Targets the ~3.2 TB/s scattered-access ceiling seen in r6-r11.

typedef __attribute__((ext_vector_type(8))) short short8;   // 8 bf16
typedef __attribute__((ext_vector_type(4))) float floatx4;  // MFMA C/D

namespace {
constexpr int Bn = 128, Sn = 672, Pn = 168, Cn = 500;
constexpr int XQ = Bn * Sn;           // 86016 ushorts per c-plane
constexpr int TC = 64, TS = 96, TROW = TS + 12;   // xpose tile
constexpr int NS  = Sn / 32;          // 21 s-chunks (MFMA K=32)
constexpr int NPT = 11;               // p-tiles of 16 (last half-masked)
constexpr int WROW = 680;             // LDS W row pitch in ushorts (672+8 pad)
}

__device__ __forceinline__ unsigned short f2bf(float f) {  // RTNE f32->bf16
  unsigned int u = __builtin_bit_cast(unsigned int, f);
  u += 0x7fffu + ((u >> 16) & 1u);
  return (unsigned short)(u >> 16);
}

// ---------------------------------------------------------------- xpose ----
// plain linear x' (r7 version, no swizzle — gemm reads A into registers now)
__global__ __launch_bounds__(256)
void xpose_kernel(const float* __restrict__ x, unsigned short* __restrict__ xq) {
  __shared__ unsigned short T[TC][TROW];
  const int b  = blockIdx.x;
  const int s0 = blockIdx.y * TS;
  const int c0 = blockIdx.z * TC;
  const int t  = threadIdx.x;

  #pragma unroll
  for (int i = 0; i < 6; ++i) {
    const int idx = t + i * 256;       // 96 s-rows x 16 c-quads
    const int sr  = idx >> 4;
    const int cq  = (idx & 15) * 4;
    int c = c0 + cq;
    if (c > Cn - 4) c = Cn - 4;        // clamp (16B-aligned); dup writes identical
    const int rel = c - c0;
    const float4 xv = *(const float4*)&x[(size_t)(b * Sn + s0 + sr) * Cn + c];
    const float4 xl = *(const float4*)&x[(size_t)(b * Sn + (Sn - 1)) * Cn + c];
    T[rel + 0][sr] = f2bf(xv.x - xl.x);
    T[rel + 1][sr] = f2bf(xv.y - xl.y);
    T[rel + 2][sr] = f2bf(xv.z - xl.z);
    T[rel + 3][sr] = f2bf(xv.w - xl.w);
  }
  __syncthreads();
  #pragma unroll
  for (int i = 0; i < 6; ++i) {
    const int idx = t + i * 256;       // 64 c-rows x 24 s-quads
    const int cr  = idx / 24;
    const int sq  = (idx % 24) * 4;
    const int c   = c0 + cr;
    if (c >= Cn) continue;
    const ushort4 v = *(const ushort4*)&T[cr][sq];
    *(ushort4*)&xq[(size_t)c * XQ + b * Sn + s0 + sq] = v;
  }
}

// ----------------------------------------------------------------- gemm ----
// Barrier waits LDS only; vmem waits are compiler-counted per register use.
#define BAR_LGKM() asm volatile("s_waitcnt lgkmcnt(0)\n\ts_barrier" ::: "memory")

__global__ __launch_bounds__(512, 2)
void gemm_kernel(const unsigned short* __restrict__ xq, const float* __restrict__ W,
                 const float* __restrict__ bias, const float* __restrict__ x,
                 float* __restrict__ out) {
  __shared__ unsigned short Wl[2][16 * WROW];   // 2 x 21.25 KB, bf16, padded rows
  __shared__ float xl_l[Bn];
  __shared__ float bi_l[Pn];

  // bijective XCD remap: consecutive c-planes co-run on one XCD (write merge)
  const int bid = blockIdx.x;
  const int xcd = bid & 7, sub = bid >> 3;
  const int c0  = xcd * 62 + (xcd < 4 ? xcd : 4) + sub;   // 0..499

  const int tid  = threadIdx.x;
  const int lane = tid & 63;
  const int wv   = tid >> 6;           // wave owns b in [16*wv, 16*wv+16)
  const int r16  = lane & 15;
  const int kg   = lane >> 4;

  // ---- W staging descriptors: 2688 float4 per p-tile, 6 per thread ----
  int wrow[6], wcol[6];                 // row 0..15, col4 0..167 (fixed across tiles)
  #pragma unroll
  for (int k = 0; k < 6; ++k) {
    const int f = tid + 512 * k;        // k=5 valid only for tid<128
    wrow[k] = f / 168;
    wcol[k] = f % 168;
  }
  const bool w5 = tid < 128;
  float4 wreg[6];                       // single staging set (static indices)

  auto loadW = [&](int pt) {
    #pragma unroll
    for (int k = 0; k < 6; ++k) {
      if (k == 5 && !w5) continue;
      int row = pt * 16 + wrow[k];
      if (row > Pn - 1) row = Pn - 1;   // tail p-tile clamp (stores masked)
      wreg[k] = *(const float4*)&W[((size_t)c0 * Pn + row) * Sn + wcol[k] * 4];
    }
  };
  auto writeW = [&](int buf) {
    #pragma unroll
    for (int k = 0; k < 6; ++k) {
      if (k == 5 && !w5) continue;
      ushort4 u;
      u.x = f2bf(wreg[k].x); u.y = f2bf(wreg[k].y);
      u.z = f2bf(wreg[k].z); u.w = f2bf(wreg[k].w);
      *(ushort4*)&Wl[buf][wrow[k] * WROW + wcol[k] * 4] = u;
    }
  };

  // ---- prologue: W(0) first (critical), then xlast/bias, then A preload ----
  loadW(0);

  if (tid < Bn) xl_l[tid] = x[((size_t)tid * Sn + (Sn - 1)) * Cn + c0];
  else if (tid < Bn + Pn) bi_l[tid - Bn] = bias[(size_t)c0 * Pn + (tid - Bn)];

  const unsigned short* aBase = xq + (size_t)c0 * XQ + (wv * 16 + r16) * Sn + kg * 8;
  short8 aR[NS];                        // 84 VGPR, resident for whole kernel
  #pragma unroll
  for (int s = 0; s < NS; ++s) aR[s] = *(const short8*)(aBase + s * 32);

  writeW(0);                            // waits only the 6 W(0) regs (counted)
  loadW(1);                             // reuse wreg (WAR after ds_write issue)
  BAR_LGKM();                           // LDS visible; W(1)/A loads stay in flight

  // ---- main loop over p-tiles ----
  #pragma unroll 1
  for (int pt = 0; pt < NPT; ++pt) {
    const int buf = pt & 1;

    if (pt + 1 < NPT) {
      writeW(buf ^ 1);                  // stage W(pt+1): counted wait on wreg
      if (pt + 2 < NPT) loadW(pt + 2);  // issue next stream chunk
    }

    floatx4 acc = (floatx4){0.f, 0.f, 0.f, 0.f};
    const int rdb = r16 * WROW + kg * 8;
    #pragma unroll
    for (int s = 0; s < NS; ++s) {      // fully unrolled: aR[s] static
      const short8 wf = *(const short8*)&Wl[buf][rdb + s * 32];
      acc = __builtin_amdgcn_mfma_f32_16x16x32_bf16(aR[s], wf, acc, 0, 0, 0);
    }

    // epilogue for this p-tile: D col = r16 (=p), row = kg*4+r (=b offset)
    const int p = pt * 16 + r16;
    if (p < Pn) {
      const float bi = bi_l[p];
      #pragma unroll
      for (int r = 0; r < 4; ++r) {
        const int b = wv * 16 + kg * 4 + r;
        out[((size_t)b * Pn + p) * Cn + c0] = acc[r] + bi + xl_l[b];
      }
    }

    if (pt + 1 < NPT) BAR_LGKM();       // next tile's LDS ready; no vmcnt drain
  }
}

extern "C" void kernel_launch(void* const* d_in, const int* in_sizes, int n_in,
                              void* d_out, int out_size, void* d_ws, size_t ws_size,
                              hipStream_t stream) {
  (void)in_sizes; (void)n_in; (void)out_size; (void)ws_size;  // needs ws >= 86,016,000 B
  const float* x  = (const float*)d_in[0];
  const float* W  = (const float*)d_in[1];
  const float* bv = (const float*)d_in[2];
  float* out = (float*)d_out;
  unsigned short* xq = (unsigned short*)d_ws;

  hipLaunchKernelGGL(xpose_kernel, dim3(Bn, Sn / TS, (Cn + TC - 1) / TC), dim3(256), 0, stream,
                     x, xq);
  hipLaunchKernelGGL(gemm_kernel, dim3(Cn), dim3(512), 0, stream,
                     xq, W, bv, x, out);
}